// Round 4
// baseline (295.510 us; speedup 1.0000x reference)
//
#include <hip/hip_runtime.h>

// B=32, C=3, H=W=512, window 11, sigma 1.5, VALID conv -> 502x502
#define H 512
#define W 512
#define OUT_Wc 502
#define OUT_Hc 502
#define C1c 1.0e-4f   // (0.01*1)^2
#define C2c 9.0e-4f   // (0.03*1)^2

#define TH 56             // output rows per block (9 y-tiles cover 502..504)
#define NR 66             // TH+10 input rows, multiple of 11 (phase-aligned)
#define RSTRIDE 128       // 64 main cols + halo; padded so unconditional halo
                          // writes (lane 0..63 -> [64..127]) never alias main

// Barrier-free row-streaming SSIM, take 2:
//  - each WAVE owns 64 output columns + private LDS ring -> no __syncthreads.
//    Intra-wave DS ops are in-order; __builtin_amdgcn_wave_barrier() pins
//    compiler ordering of ds_write before ds_read.
//  - NO divergence in the row loop: halo loads/stores are unconditional for
//    all 64 lanes (addresses clamped, loop-invariant); dead-lane halo writes
//    land in ring padding ([74..127]) and are never read.
//  - prefetch distance 2 (parity register pairs): ~2 rows of compute between
//    global load issue and LDS staging -> hides HBM latency, no barrier drain.
//  - launch_bounds(256,4): 128-VGPR budget; live state ~85 regs, no spill
//    (R3's (256,5)=48 VGPRs spilled and regressed).
__global__ __launch_bounds__(256, 4) void ssim_kernel(const float* __restrict__ img1,
                                                      const float* __restrict__ img2,
                                                      float* __restrict__ out) {
    __shared__ float2 ring[4][2][RSTRIDE];   // [wave][slot][col], 8 KiB

    // normalized Gaussian, sigma=1.5, ws=11 (matches reference to ~1e-7)
    constexpr float GW[11] = {0.00102838f, 0.00759876f, 0.03600078f, 0.10936067f,
                              0.21300555f, 0.26601174f, 0.21300555f, 0.10936067f,
                              0.03600078f, 0.00759876f, 0.00102838f};

    const int tid  = threadIdx.x;
    const int wv   = tid >> 6;
    const int lane = tid & 63;

    const int plane = blockIdx.z;                 // b*3 + c
    const size_t pbase = (size_t)plane * (H * W);
    const float* __restrict__ p1 = img1 + pbase;
    const float* __restrict__ p2 = img2 + pbase;

    const int Y0    = blockIdx.y * TH;
    const int wcol0 = (blockIdx.x * 4 + wv) * 64;     // wave's first column
    const int gx    = wcol0 + lane;                   // 0..511 (loop-invariant)
    const int hx    = min(wcol0 + 64 + lane, W - 1);  // halo col, clamped, loop-invariant

    float2 (* __restrict__ wring)[RSTRIDE] = ring[wv];

    float acc0[11], acc1[11], acc2[11], acc3[11], acc4[11];
#pragma unroll
    for (int i = 0; i < 11; ++i) { acc0[i]=0.f; acc1[i]=0.f; acc2[i]=0.f; acc3[i]=0.f; acc4[i]=0.f; }

    const bool colok = (gx < OUT_Wc);
    float lsum = 0.f;

    // prime prefetch: rows 0 and 1 into parity slots (Y0+1 <= 449, in range)
    float pa1[2], pa2[2], pb1[2], pb2[2];
    {
        const float* r0a = p1 + (size_t)Y0 * W;
        const float* r0b = p2 + (size_t)Y0 * W;
        pa1[0] = r0a[gx]; pa2[0] = r0b[gx];
        pb1[0] = r0a[hx]; pb2[0] = r0b[hx];
        const float* r1a = p1 + (size_t)(Y0 + 1) * W;
        const float* r1b = p2 + (size_t)(Y0 + 1) * W;
        pa1[1] = r1a[gx]; pa2[1] = r1b[gx];
        pb1[1] = r1a[hx]; pb2[1] = r1b[hx];
    }

#pragma unroll 1
    for (int rb = 0; rb < NR; rb += 11) {
#pragma unroll
        for (int p = 0; p < 11; ++p) {
            const int r = rb + p;
            const int slot = r & 1;

            // stage row r (loaded 2 iterations ago) — unconditional, no masks
            wring[slot][lane]      = make_float2(pa1[slot], pa2[slot]);
            wring[slot][64 + lane] = make_float2(pb1[slot], pb2[slot]);

            // prefetch row r+2 into the same parity slot (uniform SALU base)
            {
                const int gy = min(Y0 + r + 2, H - 1);   // clamp keeps loads in-bounds
                const float* __restrict__ n1 = p1 + (size_t)gy * W;
                const float* __restrict__ n2 = p2 + (size_t)gy * W;
                pa1[slot] = n1[gx]; pa2[slot] = n2[gx];
                pb1[slot] = n1[hx]; pb2[slot] = n2[hx];
            }

            __builtin_amdgcn_wave_barrier();   // pin ds_writes before ds_reads

            // horizontal 11-tap conv of 5 quantities (products on the fly)
            float h0, h1, h2, h3, h4;
#pragma unroll
            for (int t = 0; t < 11; ++t) {
                const float2 v = wring[slot][lane + t];
                const float w = GW[t];
                if (t == 0) {
                    h0 = w * v.x;         h1 = w * v.y;
                    h2 = w * (v.x * v.x); h3 = w * (v.y * v.y);
                    h4 = w * (v.x * v.y);
                } else {
                    h0 = fmaf(w, v.x,       h0);
                    h1 = fmaf(w, v.y,       h1);
                    h2 = fmaf(w, v.x * v.x, h2);
                    h3 = fmaf(w, v.y * v.y, h3);
                    h4 = fmaf(w, v.x * v.y, h4);
                }
            }

            // vertical scatter: slot a gets weight GW[(p-a) mod 11];
            // slot a==p starts a fresh window -> init by mul (no resets)
#pragma unroll
            for (int a = 0; a < 11; ++a) {
                const float w = GW[(p - a + 11) % 11];   // compile-time
                if (a == p) {
                    acc0[a] = w * h0; acc1[a] = w * h1; acc2[a] = w * h2;
                    acc3[a] = w * h3; acc4[a] = w * h4;
                } else {
                    acc0[a] = fmaf(w, h0, acc0[a]);
                    acc1[a] = fmaf(w, h1, acc1[a]);
                    acc2[a] = fmaf(w, h2, acc2[a]);
                    acc3[a] = fmaf(w, h3, acc3[a]);
                    acc4[a] = fmaf(w, h4, acc4[a]);
                }
            }

            // output row oy = Y0 + r - 10 completes in slot e = (p+1)%11
            const int e = (p + 1) % 11;
            const int oy = Y0 + r - 10;
            if (r >= 10 && oy < OUT_Hc) {          // uniform branch
                const float m1 = acc0[e], m2 = acc1[e];
                const float m12 = m1 * m2;
                const float sig12 = fmaf(-m1, m2, acc4[e]);
                const float num_a = fmaf(2.f, m12,   C1c);
                const float num_b = fmaf(2.f, sig12, C2c);
                const float den_a = fmaf(m1, m1, fmaf(m2, m2, C1c));
                const float den_b = (fmaf(-m1, m1, acc2[e]) + fmaf(-m2, m2, acc3[e])) + C2c;
                const float v = (num_a * num_b) * __builtin_amdgcn_rcpf(den_a * den_b);
                lsum += colok ? v : 0.f;
            }
        }
    }

    // per-wave reduce + one atomic per wave
#pragma unroll
    for (int off = 32; off > 0; off >>= 1) lsum += __shfl_down(lsum, off, 64);
    if (lane == 0) {
        const float inv_count = 1.0f / (3.0f * (float)OUT_Hc * (float)OUT_Wc);
        atomicAdd(&out[plane / 3], lsum * inv_count);
    }
}

__global__ void zero_out(float* out, int n) {
    int i = threadIdx.x + blockIdx.x * blockDim.x;
    if (i < n) out[i] = 0.f;
}

extern "C" void kernel_launch(void* const* d_in, const int* in_sizes, int n_in,
                              void* d_out, int out_size, void* d_ws, size_t ws_size,
                              hipStream_t stream) {
    const float* img1 = (const float*)d_in[0];
    const float* img2 = (const float*)d_in[1];
    float* out = (float*)d_out;

    zero_out<<<1, 64, 0, stream>>>(out, out_size);

    const int nplanes = in_sizes[0] / (H * W);     // 96
    dim3 grid(2,                                   // 2 * 4 waves * 64 cols = 512
              (OUT_Hc + TH - 1) / TH,              // 9
              nplanes);
    ssim_kernel<<<grid, 256, 0, stream>>>(img1, img2, out);
}

// Round 5
// 271.296 us; speedup vs baseline: 1.0893x; 1.0893x over previous
//
#include <hip/hip_runtime.h>

// B=32, C=3, H=W=512, window 11, sigma 1.5, VALID conv -> 502x502
#define H 512
#define W 512
#define OUT_Wc 502
#define OUT_Hc 502
#define C1c 1.0e-4f   // (0.01*1)^2
#define C2c 9.0e-4f   // (0.03*1)^2

#define TH 56         // output rows per block (9 y-tiles cover 504>=502)
#define NR 66         // input rows per tile = TH+10 = 3*22 (22 = lcm(2,11))
#define RW 266        // ring width: 256 main cols + 10 halo
#define HALO 10

// s/d-basis row-streaming SSIM:
//  - convolve only 4 quantities {s=x1+x2, d=x1-x2, s^2, d^2}; epilogue needs
//    just mu1,mu2,sigma12,sigma1+sigma2 which are linear in these.
//  - block-shared (s,d) ring, 4 slots; TWO rows staged per __syncthreads
//    (22-row unrolled phase loop keeps all weight indices compile-time).
//  - prefetch depth = 2 pairs: global loads issued ~2 barriers before their
//    ds_write -> vmcnt wait fully covered even at cold-HBM latency.
//  - 11 phase-slot vertical accumulators per quantity (44 regs); slot re-init
//    by MUL at its window start (row r === phase mod 11), no explicit resets.
__global__ __launch_bounds__(256, 4) void ssim_kernel(const float* __restrict__ img1,
                                                      const float* __restrict__ img2,
                                                      float* __restrict__ out) {
    __shared__ float2 ring[4][RW];   // (s,d) pairs, 4*266*8 = 8512 B

    // normalized Gaussian, sigma=1.5, ws=11 (matches reference to ~1e-7)
    constexpr float GW[11] = {0.00102838f, 0.00759876f, 0.03600078f, 0.10936067f,
                              0.21300555f, 0.26601174f, 0.21300555f, 0.10936067f,
                              0.03600078f, 0.00759876f, 0.00102838f};

    const int tid = threadIdx.x;
    const int X0 = blockIdx.x * 256;
    const int Y0 = blockIdx.y * TH;
    const int plane = blockIdx.z;                 // b*3 + c
    const size_t pbase = (size_t)plane * (H * W);
    const float* __restrict__ p1 = img1 + pbase;
    const float* __restrict__ p2 = img2 + pbase;

    const int gx = X0 + tid;                      // 0..511, loop-invariant
    const int hx = min(X0 + 256 + tid, W - 1);    // halo col (tid<10), invariant

    // 11 phase slots x 4 quantities of vertical partial sums (registers)
    float as_[11], ad_[11], aq_[11], ar_[11];     // s, d, s^2, d^2
#pragma unroll
    for (int i = 0; i < 11; ++i) { as_[i]=0.f; ad_[i]=0.f; aq_[i]=0.f; ar_[i]=0.f; }

    const bool colok = (gx < OUT_Wc);
    float lsum = 0.f;

    // ---- priming: stage rows 0,1 directly; prefetch rows 2,3 (P0) and 4,5 (P1)
    float n0a, n0b, n1a, n1b, h0a, h0b, h1a, h1b;   // P0: rows r+2, r+3
    float m0a, m0b, m1a, m1b, k0a, k0b, k1a, k1b;   // P1: rows r+4, r+5
    {
        const float* r0a = p1 + (size_t)Y0 * W;
        const float* r0b = p2 + (size_t)Y0 * W;
        const float* r1a = r0a + W;
        const float* r1b = r0b + W;
        float x0a = r0a[gx], x0b = r0b[gx], x1a = r1a[gx], x1b = r1b[gx];
        ring[0][tid] = make_float2(x0a + x0b, x0a - x0b);
        ring[1][tid] = make_float2(x1a + x1b, x1a - x1b);
        if (tid < HALO) {
            float y0a = r0a[hx], y0b = r0b[hx], y1a = r1a[hx], y1b = r1b[hx];
            ring[0][256 + tid] = make_float2(y0a + y0b, y0a - y0b);
            ring[1][256 + tid] = make_float2(y1a + y1b, y1a - y1b);
        }
        const float* r2a = r0a + 2 * W;  const float* r2b = r0b + 2 * W;
        const float* r3a = r0a + 3 * W;  const float* r3b = r0b + 3 * W;
        const float* r4a = r0a + 4 * W;  const float* r4b = r0b + 4 * W;
        const float* r5a = r0a + 5 * W;  const float* r5b = r0b + 5 * W;
        n0a = r2a[gx]; n0b = r2b[gx]; n1a = r3a[gx]; n1b = r3b[gx];
        m0a = r4a[gx]; m0b = r4b[gx]; m1a = r5a[gx]; m1b = r5b[gx];
        h0a=h0b=h1a=h1b=k0a=k0b=k1a=k1b=0.f;
        if (tid < HALO) {
            h0a = r2a[hx]; h0b = r2b[hx]; h1a = r3a[hx]; h1b = r3b[hx];
            k0a = r4a[hx]; k0b = r4b[hx]; k1a = r5a[hx]; k1b = r5b[hx];
        }
    }
    __syncthreads();

    // one row: h-conv (from ring) + vertical phase scatter + epilogue
#define ROW_STEP(SLOT, PH, RRT)                                               \
    {                                                                         \
        const float2* __restrict__ rp = &ring[(SLOT)][tid];                   \
        float hs, hd, hq, hr;                                                 \
        _Pragma("unroll")                                                     \
        for (int t = 0; t < 11; ++t) {                                        \
            const float2 v = rp[t];                                           \
            const float w = GW[t];                                            \
            if (t == 0) { hs = w*v.x; hd = w*v.y;                             \
                          hq = w*(v.x*v.x); hr = w*(v.y*v.y); }               \
            else { hs = fmaf(w, v.x, hs); hd = fmaf(w, v.y, hd);              \
                   hq = fmaf(w, v.x*v.x, hq); hr = fmaf(w, v.y*v.y, hr); }    \
        }                                                                     \
        _Pragma("unroll")                                                     \
        for (int a = 0; a < 11; ++a) {                                        \
            const float w = GW[((PH) - a + 11) % 11];                         \
            if (a == (PH)) { as_[a]=w*hs; ad_[a]=w*hd; aq_[a]=w*hq; ar_[a]=w*hr; } \
            else { as_[a]=fmaf(w,hs,as_[a]); ad_[a]=fmaf(w,hd,ad_[a]);        \
                   aq_[a]=fmaf(w,hq,aq_[a]); ar_[a]=fmaf(w,hr,ar_[a]); }      \
        }                                                                     \
        const int e = ((PH) + 1) % 11;                                        \
        const int oy = Y0 + (RRT) - 10;                                       \
        if ((RRT) >= 10 && oy < OUT_Hc) {                                     \
            const float ms = as_[e], md = ad_[e], qs = aq_[e], qd = ar_[e];   \
            const float A = ms * ms, B = md * md;                             \
            const float u = A - B, vv = A + B;                                \
            const float w2 = qs - qd, z = qs + qd;                            \
            const float num_a = fmaf(0.5f, u, C1c);                           \
            const float den_a = fmaf(0.5f, vv, C1c);                          \
            const float num_b = fmaf(0.5f, w2 - u, C2c);                      \
            const float den_b = fmaf(0.5f, z - vv, C2c);                      \
            const float val = (num_a * num_b) * __builtin_amdgcn_rcpf(den_a * den_b); \
            lsum += colok ? val : 0.f;                                        \
        }                                                                     \
    }

#pragma unroll 1
    for (int rb = 0; rb < NR; rb += 22) {
#pragma unroll
        for (int pp = 0; pp < 11; ++pp) {
            const int p = 2 * pp;            // pair covers rows r, r+1
            const int r = rb + p;

            // (a) issue loads for rows r+6, r+7 (clamped; tail loads harmless)
            const int gy6 = min(Y0 + r + 6, H - 1);
            const int gy7 = min(Y0 + r + 7, H - 1);
            const float* __restrict__ A6 = p1 + (size_t)gy6 * W;
            const float* __restrict__ B6 = p2 + (size_t)gy6 * W;
            const float* __restrict__ A7 = p1 + (size_t)gy7 * W;
            const float* __restrict__ B7 = p2 + (size_t)gy7 * W;
            const float t0a = A6[gx], t0b = B6[gx], t1a = A7[gx], t1b = B7[gx];
            float u0a = 0.f, u0b = 0.f, u1a = 0.f, u1b = 0.f;
            if (tid < HALO) { u0a = A6[hx]; u0b = B6[hx]; u1a = A7[hx]; u1b = B7[hx]; }

            // (b) stage rows r+2, r+3 from P0 (loaded 2 pairs ago)
            const int s2 = (r + 2) & 3, s3 = (r + 3) & 3;
            ring[s2][tid] = make_float2(n0a + n0b, n0a - n0b);
            ring[s3][tid] = make_float2(n1a + n1b, n1a - n1b);
            if (tid < HALO) {
                ring[s2][256 + tid] = make_float2(h0a + h0b, h0a - h0b);
                ring[s3][256 + tid] = make_float2(h1a + h1b, h1a - h1b);
            }
            // rotate prefetch: P0 <- P1 <- fresh
            n0a = m0a; n0b = m0b; n1a = m1a; n1b = m1b;
            h0a = k0a; h0b = k0b; h1a = k1a; h1b = k1b;
            m0a = t0a; m0b = t0b; m1a = t1a; m1b = t1b;
            k0a = u0a; k0b = u0b; k1a = u1a; k1b = u1b;

            // (c) compute rows r (phase 2pp%11) and r+1 (phase (2pp+1)%11)
            ROW_STEP((r) & 3,     (2 * pp) % 11,     r);
            ROW_STEP((r + 1) & 3, (2 * pp + 1) % 11, r + 1);

            // (d) make rows r+2, r+3 visible
            __syncthreads();
        }
    }
#undef ROW_STEP

    // per-wave reduce + one atomic per wave
#pragma unroll
    for (int off = 32; off > 0; off >>= 1) lsum += __shfl_down(lsum, off, 64);
    if ((tid & 63) == 0) {
        const float inv_count = 1.0f / (3.0f * (float)OUT_Hc * (float)OUT_Wc);
        atomicAdd(&out[plane / 3], lsum * inv_count);
    }
}

__global__ void zero_out(float* out, int n) {
    int i = threadIdx.x + blockIdx.x * blockDim.x;
    if (i < n) out[i] = 0.f;
}

extern "C" void kernel_launch(void* const* d_in, const int* in_sizes, int n_in,
                              void* d_out, int out_size, void* d_ws, size_t ws_size,
                              hipStream_t stream) {
    const float* img1 = (const float*)d_in[0];
    const float* img2 = (const float*)d_in[1];
    float* out = (float*)d_out;

    zero_out<<<1, 64, 0, stream>>>(out, out_size);

    const int nplanes = in_sizes[0] / (H * W);     // 96
    dim3 grid(2,                                   // 2 x 256 cols = 512
              (OUT_Hc + TH - 1) / TH,              // 9
              nplanes);
    ssim_kernel<<<grid, 256, 0, stream>>>(img1, img2, out);
}